// Round 6
// baseline (341.656 us; speedup 1.0000x reference)
//
#include <hip/hip_runtime.h>
#include <hip/hip_bf16.h>

typedef __bf16 bf16x8 __attribute__((ext_vector_type(8)));
typedef float f32x4 __attribute__((ext_vector_type(4)));
typedef unsigned short ushort_t;

#define S_LEN 4096
#define D_DIM 512
#define NBATCH 4
#define NROW (NBATCH * S_LEN)

static __device__ __forceinline__ ushort_t f2bf(float f) {
    __hip_bfloat16 h = __float2bfloat16(f);
    return __builtin_bit_cast(ushort_t, h);
}

// ---------------- fp32 -> bf16 convert (with optional scale) ----------------
__global__ void cvt_bf16_kernel(const float* __restrict__ src, ushort_t* __restrict__ dst,
                                int n4, float scale) {
    int i = blockIdx.x * blockDim.x + threadIdx.x;
    if (i >= n4) return;
    float4 v = reinterpret_cast<const float4*>(src)[i];
    ushort4 o;
    o.x = f2bf(v.x * scale);
    o.y = f2bf(v.y * scale);
    o.z = f2bf(v.z * scale);
    o.w = f2bf(v.w * scale);
    reinterpret_cast<ushort4*>(dst)[i] = o;
}

// ---------------- generic bf16 GEMM: C[M][N] = A[M][K] * Bt[N][K]^T ----------------
__global__ __launch_bounds__(256) void gemm_bt(const ushort_t* __restrict__ A,
                                               const ushort_t* __restrict__ Bt,
                                               ushort_t* __restrict__ C,
                                               int M, int N, int K) {
    __shared__ ushort_t As[128 * 40];
    __shared__ ushort_t Bs[128 * 40];
    int tid = threadIdx.x;
    int w = tid >> 6, lane = tid & 63, c = lane & 15, g = lane >> 4;
    int m0 = blockIdx.x * 128, n0 = blockIdx.y * 128;
    int wm = (w >> 1) * 64, wn = (w & 1) * 64;

    f32x4 acc[4][4];
#pragma unroll
    for (int mi = 0; mi < 4; mi++)
#pragma unroll
        for (int ni = 0; ni < 4; ni++) acc[mi][ni] = (f32x4){0.f, 0.f, 0.f, 0.f};

    for (int k0 = 0; k0 < K; k0 += 32) {
        __syncthreads();
#pragma unroll
        for (int r = 0; r < 2; r++) {
            int cl = r * 256 + tid;
            int row = cl >> 2, cin = cl & 3;
            *(bf16x8*)(&As[row * 40 + cin * 8]) =
                *(const bf16x8*)(A + (size_t)(m0 + row) * K + k0 + cin * 8);
            *(bf16x8*)(&Bs[row * 40 + cin * 8]) =
                *(const bf16x8*)(Bt + (size_t)(n0 + row) * K + k0 + cin * 8);
        }
        __syncthreads();

        bf16x8 af[4], bfr[4];
#pragma unroll
        for (int i2 = 0; i2 < 4; i2++)
            af[i2] = *(const bf16x8*)(&As[(wm + i2 * 16 + c) * 40 + g * 8]);
#pragma unroll
        for (int i2 = 0; i2 < 4; i2++)
            bfr[i2] = *(const bf16x8*)(&Bs[(wn + i2 * 16 + c) * 40 + g * 8]);
#pragma unroll
        for (int mi = 0; mi < 4; mi++)
#pragma unroll
            for (int ni = 0; ni < 4; ni++)
                acc[mi][ni] = __builtin_amdgcn_mfma_f32_16x16x32_bf16(af[mi], bfr[ni],
                                                                      acc[mi][ni], 0, 0, 0);
    }

#pragma unroll
    for (int mi = 0; mi < 4; mi++)
#pragma unroll
        for (int ni = 0; ni < 4; ni++)
#pragma unroll
            for (int j = 0; j < 4; j++)
                C[(size_t)(m0 + wm + mi * 16 + g * 4 + j) * N + n0 + wn + ni * 16 + c] =
                    f2bf(acc[mi][ni][j]);
}

// ------------- flash attention partials: all-wave QK (kv-half split), D-split PV -------------
// 256 WGs of 512 threads. WG (b, p, h): q-blocks j=p then 63-p; kv tiles t%2==h (KVB=64).
// Waves = (row-group r 0..3, half d 0..1). Staging: d0->K, d1->V.
// QK: wave (r,d) computes S[16 rows of r][32 kv-cols of d] -- no redundancy, no idle waves.
// Softmax row stats combined across the d-pair via tiny LDS arrays (2 barriers).
// PV: all 8 waves, D-half d. Raw partials merged by attn_merge_kernel.
#define KVB 64
#define KPAD 520   // K tile row pad (ushorts)
#define VPAD 72    // V^T tile row pad (ushorts)
#define PPAD 72

__global__ __launch_bounds__(512, 2) void attn_part_kernel(const ushort_t* __restrict__ Q,
                                                           const ushort_t* __restrict__ K,
                                                           const ushort_t* __restrict__ Vt,
                                                           float* __restrict__ out0,
                                                           float* __restrict__ out1,
                                                           float* __restrict__ ml) {
    __shared__ ushort_t Ks[KVB * KPAD];       // 66560 B
    __shared__ ushort_t Vs[D_DIM * VPAD];     // 73728 B
    __shared__ ushort_t Ps[4 * 16 * PPAD];    //  9216 B
    __shared__ float mhalf[2 * 64];           //   512 B
    __shared__ float lhalf[2 * 64];           //   512 B

    const int gid = blockIdx.x;
    const int b = gid & 3;
    const int h = (gid >> 2) & 1;
    const int p = gid >> 3;            // 0..31
    const int tid = threadIdx.x;
    const int ttid = tid & 255;
    const int w = tid >> 6, lane = tid & 63, c = lane & 15, g = lane >> 4;
    const int r = w & 3, d = w >> 2;   // row-group, kv-half / D-half

    const int sbase = b * S_LEN;
    ushort_t* pw = Ps + r * 16 * PPAD;
    float* po = h ? out1 : out0;

    for (int phase = 0; phase < 2; ++phase) {
        const int jblk = phase ? (63 - p) : p;
        const int qbase = jblk * 64;

        // Q fragments (1/sqrt(512) folded into W_q); d-pair waves load the same 16 rows.
        bf16x8 qf[16];
        {
            const ushort_t* qrow = Q + (size_t)(sbase + qbase + r * 16 + c) * D_DIM;
#pragma unroll
            for (int kk = 0; kk < 16; kk++)
                qf[kk] = *(const bf16x8*)(qrow + kk * 32 + g * 8);
        }

        f32x4 o[16];
#pragma unroll
        for (int t = 0; t < 16; t++) o[t] = (f32x4){0.f, 0.f, 0.f, 0.f};
        float m_r[4], l_r[4];
#pragma unroll
        for (int jj = 0; jj < 4; jj++) { m_r[jj] = -1e30f; l_r[jj] = 0.f; }

        for (int t = h; t <= jblk; t += 2) {
            const int kv0 = t * KVB;
            __syncthreads();   // B1: safe to overwrite Ks/Vs (prev PV done)
            // ---- stage: d0 waves -> K tile [64][512]; d1 waves -> V^T tile [512][64] ----
            if (d == 0) {
                const ushort_t* kg = K + (size_t)(sbase + kv0) * D_DIM;
#pragma unroll
                for (int rr = 0; rr < 16; rr++) {
                    int cl = rr * 256 + ttid;
                    int row = cl >> 6, cin = cl & 63;
                    *(bf16x8*)(&Ks[row * KPAD + cin * 8]) =
                        *(const bf16x8*)(kg + row * D_DIM + cin * 8);
                }
            } else {
                const ushort_t* vg = Vt + (size_t)sbase + kv0;
#pragma unroll
                for (int rr = 0; rr < 16; rr++) {
                    int cl = rr * 256 + ttid;
                    int row = cl >> 3, cin = cl & 7;
                    *(bf16x8*)(&Vs[row * VPAD + cin * 8]) =
                        *(const bf16x8*)(vg + (size_t)row * NROW + cin * 8);
                }
            }
            __syncthreads();   // B2: tiles staged

            // ---- QK^T : wave (r,d) -> S[16 q-rows of r][32 kv-cols of d] ----
            f32x4 s4[2];
#pragma unroll
            for (int nt = 0; nt < 2; nt++) {
                f32x4 acc = (f32x4){0.f, 0.f, 0.f, 0.f};
#pragma unroll
                for (int kk = 0; kk < 16; kk++) {
                    bf16x8 kf = *(const bf16x8*)(&Ks[(d * 32 + nt * 16 + c) * KPAD + kk * 32 + g * 8]);
                    acc = __builtin_amdgcn_mfma_f32_16x16x32_bf16(qf[kk], kf, acc, 0, 0, 0);
                }
                s4[nt] = acc;
            }

            // ---- causal mask (diagonal tile only) ----
            if (t == jblk) {
#pragma unroll
                for (int nt = 0; nt < 2; nt++)
#pragma unroll
                    for (int jj = 0; jj < 4; jj++) {
                        int qrow = qbase + r * 16 + g * 4 + jj;
                        int kvcol = kv0 + d * 32 + nt * 16 + c;
                        if (kvcol > qrow) s4[nt][jj] = -1e38f;
                    }
            }

            // ---- local (half) row max ----
            float mx[4];
#pragma unroll
            for (int jj = 0; jj < 4; jj++) {
                float v = fmaxf(s4[0][jj], s4[1][jj]);
#pragma unroll
                for (int off = 1; off < 16; off <<= 1) v = fmaxf(v, __shfl_xor(v, off, 64));
                mx[jj] = v;
            }
            if (c == 0) {
#pragma unroll
                for (int jj = 0; jj < 4; jj++)
                    mhalf[d * 64 + r * 16 + g * 4 + jj] = mx[jj];
            }
            __syncthreads();   // B3: both halves' maxima visible

            // ---- combine max, exp, P-write, local sum ----
            float alpha[4], rs[4];
#pragma unroll
            for (int jj = 0; jj < 4; jj++) {
                float mo = mhalf[(1 ^ d) * 64 + r * 16 + g * 4 + jj];
                float mn = fmaxf(m_r[jj], fmaxf(mx[jj], mo));
                alpha[jj] = __expf(m_r[jj] - mn);   // == 1.0f exactly when max unchanged
                m_r[jj] = mn;
                rs[jj] = 0.f;
            }
#pragma unroll
            for (int nt = 0; nt < 2; nt++)
#pragma unroll
                for (int jj = 0; jj < 4; jj++) {
                    float pv = __expf(s4[nt][jj] - m_r[jj]);
                    rs[jj] += pv;
                    pw[(g * 4 + jj) * PPAD + d * 32 + nt * 16 + c] = f2bf(pv);
                }
#pragma unroll
            for (int jj = 0; jj < 4; jj++) {
                float v = rs[jj];
#pragma unroll
                for (int off = 1; off < 16; off <<= 1) v += __shfl_xor(v, off, 64);
                rs[jj] = v;
            }
            if (c == 0) {
#pragma unroll
                for (int jj = 0; jj < 4; jj++)
                    lhalf[d * 64 + r * 16 + g * 4 + jj] = rs[jj];
            }
            __syncthreads();   // B4: P tile + both halves' sums visible

#pragma unroll
            for (int jj = 0; jj < 4; jj++) {
                float lo = lhalf[(1 ^ d) * 64 + r * 16 + g * 4 + jj];
                l_r[jj] = l_r[jj] * alpha[jj] + rs[jj] + lo;
            }

            // ---- rescale O (skipped wave-uniformly when all alphas == 1) ----
            bool need = !(alpha[0] == 1.f && alpha[1] == 1.f && alpha[2] == 1.f && alpha[3] == 1.f);
            if (__any((int)need)) {
#pragma unroll
                for (int dt = 0; dt < 16; dt++)
#pragma unroll
                    for (int jj = 0; jj < 4; jj++) o[dt][jj] *= alpha[jj];
            }

            // ---- PV : O[16 rows][256 cols (d-half)] += P[16x64] * V[64x256] ----
            bf16x8 pf[2];
#pragma unroll
            for (int kk = 0; kk < 2; kk++)
                pf[kk] = *(const bf16x8*)(&pw[c * PPAD + kk * 32 + g * 8]);
#pragma unroll
            for (int dt = 0; dt < 16; dt++) {
                f32x4 acc = o[dt];
#pragma unroll
                for (int kk = 0; kk < 2; kk++) {
                    bf16x8 vf = *(const bf16x8*)(&Vs[(d * 256 + dt * 16 + c) * VPAD + kk * 32 + g * 8]);
                    acc = __builtin_amdgcn_mfma_f32_16x16x32_bf16(pf[kk], vf, acc, 0, 0, 0);
                }
                o[dt] = acc;
            }
        }

        // ---- write raw partial + (m,l) for this q-block ----
#pragma unroll
        for (int dt = 0; dt < 16; dt++)
#pragma unroll
            for (int jj = 0; jj < 4; jj++)
                po[(size_t)(sbase + qbase + r * 16 + g * 4 + jj) * D_DIM +
                   d * 256 + dt * 16 + c] = o[dt][jj];
        if (d == 0 && c == 0) {
#pragma unroll
            for (int jj = 0; jj < 4; jj++) {
                int row = sbase + qbase + r * 16 + g * 4 + jj;
                ml[((size_t)h * NROW + row) * 2 + 0] = m_r[jj];
                ml[((size_t)h * NROW + row) * 2 + 1] = l_r[jj];
            }
        }
    }
}

// ---------------- merge the two h-split partials ----------------
__global__ __launch_bounds__(256) void attn_merge_kernel(float* __restrict__ out,
                                                         const float* __restrict__ part1,
                                                         const float* __restrict__ ml) {
    int i = blockIdx.x * blockDim.x + threadIdx.x;   // float4 index
    int row = i >> 7;                                 // 128 float4 per row
    float m0 = ml[(size_t)row * 2 + 0], l0 = ml[(size_t)row * 2 + 1];
    float m1 = ml[((size_t)NROW + row) * 2 + 0], l1 = ml[((size_t)NROW + row) * 2 + 1];
    float mm = fmaxf(m0, m1);
    float a0 = __expf(m0 - mm), a1 = __expf(m1 - mm);
    float inv = 1.f / (l0 * a0 + l1 * a1);
    float4 x0 = reinterpret_cast<float4*>(out)[i];
    float4 x1 = reinterpret_cast<const float4*>(part1)[i];
    float4 r;
    r.x = (x0.x * a0 + x1.x * a1) * inv;
    r.y = (x0.y * a0 + x1.y * a1) * inv;
    r.z = (x0.z * a0 + x1.z * a1) * inv;
    r.w = (x0.w * a0 + x1.w * a1) * inv;
    reinterpret_cast<float4*>(out)[i] = r;
}

// ---------------- host launch ----------------
extern "C" void kernel_launch(void* const* d_in, const int* in_sizes, int n_in,
                              void* d_out, int out_size, void* d_ws, size_t ws_size,
                              hipStream_t stream) {
    const float* X  = (const float*)d_in[0];
    const float* Wq = (const float*)d_in[1];
    const float* Wk = (const float*)d_in[2];
    const float* Wv = (const float*)d_in[3];
    float* out = (float*)d_out;

    const int M = NROW;             // 16384
    const int Kd = D_DIM;           // 512
    const size_t XBF_BYTES = (size_t)M * Kd * 2;
    const size_t W_BYTES   = (size_t)Kd * Kd * 2;

    char* p = (char*)d_ws;
    ushort_t* Xbf = (ushort_t*)p;              p += XBF_BYTES;
    ushort_t* Wqb = (ushort_t*)p;              p += W_BYTES;
    ushort_t* Wkb = (ushort_t*)p;              p += W_BYTES;
    ushort_t* Wvb = (ushort_t*)p;              p += W_BYTES;
    ushort_t* Qb  = (ushort_t*)p;              p += XBF_BYTES;
    ushort_t* Kb  = (ushort_t*)p;              p += XBF_BYTES;
    ushort_t* Vtb = (ushort_t*)p;              p += XBF_BYTES;
    float*    part1 = (float*)p;               p += (size_t)M * Kd * 4;  // 32 MB
    float*    ml    = (float*)p;               p += (size_t)2 * M * 2 * 4;

    const float qscale = 0.044194173824159216f;  // 1/sqrt(512)

    {
        int n4 = (M * Kd) / 4;
        cvt_bf16_kernel<<<(n4 + 255) / 256, 256, 0, stream>>>(X, Xbf, n4, 1.0f);
        int w4 = (Kd * Kd) / 4;
        cvt_bf16_kernel<<<(w4 + 255) / 256, 256, 0, stream>>>(Wq, Wqb, w4, qscale);
        cvt_bf16_kernel<<<(w4 + 255) / 256, 256, 0, stream>>>(Wk, Wkb, w4, 1.0f);
        cvt_bf16_kernel<<<(w4 + 255) / 256, 256, 0, stream>>>(Wv, Wvb, w4, 1.0f);
    }
    gemm_bt<<<dim3(M / 128, Kd / 128), 256, 0, stream>>>(Xbf, Wqb, Qb, M, Kd, Kd);
    gemm_bt<<<dim3(M / 128, Kd / 128), 256, 0, stream>>>(Xbf, Wkb, Kb, M, Kd, Kd);
    gemm_bt<<<dim3(Kd / 128, M / 128), 256, 0, stream>>>(Wvb, Xbf, Vtb, Kd, M, Kd);

    attn_part_kernel<<<256, 512, 0, stream>>>(Qb, Kb, Vtb, out, part1, ml);
    attn_merge_kernel<<<(M * Kd / 4) / 256, 256, 0, stream>>>(out, part1, ml);
}

// Round 7
// 293.677 us; speedup vs baseline: 1.1634x; 1.1634x over previous
//
#include <hip/hip_runtime.h>
#include <hip/hip_bf16.h>

typedef __bf16 bf16x8 __attribute__((ext_vector_type(8)));
typedef float f32x4 __attribute__((ext_vector_type(4)));
typedef unsigned short ushort_t;

#define S_LEN 4096
#define D_DIM 512
#define NBATCH 4
#define NROW (NBATCH * S_LEN)

static __device__ __forceinline__ ushort_t f2bf(float f) {
    __hip_bfloat16 h = __float2bfloat16(f);
    return __builtin_bit_cast(ushort_t, h);
}

typedef unsigned int __attribute__((address_space(1))) as1_uint;
typedef unsigned int __attribute__((address_space(3))) as3_uint;

// async 16B/lane global->LDS (wave-uniform LDS base + lane*16; global src per-lane)
static __device__ __forceinline__ void gll16(const ushort_t* src, ushort_t* dst) {
    __builtin_amdgcn_global_load_lds((const as1_uint*)(const void*)src,
                                     (as3_uint*)(void*)dst, 16, 0, 0);
}

// ---------------- fp32 -> bf16 convert (with optional scale) ----------------
__global__ void cvt_bf16_kernel(const float* __restrict__ src, ushort_t* __restrict__ dst,
                                int n4, float scale) {
    int i = blockIdx.x * blockDim.x + threadIdx.x;
    if (i >= n4) return;
    float4 v = reinterpret_cast<const float4*>(src)[i];
    ushort4 o;
    o.x = f2bf(v.x * scale);
    o.y = f2bf(v.y * scale);
    o.z = f2bf(v.z * scale);
    o.w = f2bf(v.w * scale);
    reinterpret_cast<ushort4*>(dst)[i] = o;
}

// ---------------- generic bf16 GEMM: C[M][N] = A[M][K] * Bt[N][K]^T ----------------
__global__ __launch_bounds__(256) void gemm_bt(const ushort_t* __restrict__ A,
                                               const ushort_t* __restrict__ Bt,
                                               ushort_t* __restrict__ C,
                                               int M, int N, int K) {
    __shared__ ushort_t As[128 * 40];
    __shared__ ushort_t Bs[128 * 40];
    int tid = threadIdx.x;
    int w = tid >> 6, lane = tid & 63, c = lane & 15, g = lane >> 4;
    int m0 = blockIdx.x * 128, n0 = blockIdx.y * 128;
    int wm = (w >> 1) * 64, wn = (w & 1) * 64;

    f32x4 acc[4][4];
#pragma unroll
    for (int mi = 0; mi < 4; mi++)
#pragma unroll
        for (int ni = 0; ni < 4; ni++) acc[mi][ni] = (f32x4){0.f, 0.f, 0.f, 0.f};

    for (int k0 = 0; k0 < K; k0 += 32) {
        __syncthreads();
#pragma unroll
        for (int r = 0; r < 2; r++) {
            int cl = r * 256 + tid;
            int row = cl >> 2, cin = cl & 3;
            *(bf16x8*)(&As[row * 40 + cin * 8]) =
                *(const bf16x8*)(A + (size_t)(m0 + row) * K + k0 + cin * 8);
            *(bf16x8*)(&Bs[row * 40 + cin * 8]) =
                *(const bf16x8*)(Bt + (size_t)(n0 + row) * K + k0 + cin * 8);
        }
        __syncthreads();

        bf16x8 af[4], bfr[4];
#pragma unroll
        for (int i2 = 0; i2 < 4; i2++)
            af[i2] = *(const bf16x8*)(&As[(wm + i2 * 16 + c) * 40 + g * 8]);
#pragma unroll
        for (int i2 = 0; i2 < 4; i2++)
            bfr[i2] = *(const bf16x8*)(&Bs[(wn + i2 * 16 + c) * 40 + g * 8]);
#pragma unroll
        for (int mi = 0; mi < 4; mi++)
#pragma unroll
            for (int ni = 0; ni < 4; ni++)
                acc[mi][ni] = __builtin_amdgcn_mfma_f32_16x16x32_bf16(af[mi], bfr[ni],
                                                                      acc[mi][ni], 0, 0, 0);
    }

#pragma unroll
    for (int mi = 0; mi < 4; mi++)
#pragma unroll
        for (int ni = 0; ni < 4; ni++)
#pragma unroll
            for (int j = 0; j < 4; j++)
                C[(size_t)(m0 + wm + mi * 16 + g * 4 + j) * N + n0 + wn + ni * 16 + c] =
                    f2bf(acc[mi][ni][j]);
}

// ------------- flash attention partials: KVB=32, double-buffered K/V via global_load_lds -------------
// 256 WGs of 512 threads, 1 WG/CU. WG (b, p, h): q-blocks j=p then 63-p;
// kv tiles t (KVB=32) with t%2==h. Waves (r 0..3, d 0..1): d0 -> QK+softmax+P; all -> PV D-half.
// K LDS XOR-swizzled via pre-swizzled global src (linear dest); V linear [512][32] (conflict-free reads).
// Stage t+2 async during compute of t; 2 barriers/tile.
#define KVB 32
#define PPAD 40

__global__ __launch_bounds__(512, 2) void attn_part_kernel(const ushort_t* __restrict__ Q,
                                                           const ushort_t* __restrict__ K,
                                                           const ushort_t* __restrict__ Vt,
                                                           float* __restrict__ out0,
                                                           float* __restrict__ out1,
                                                           float* __restrict__ ml) {
    __shared__ ushort_t Ks[2][KVB][512];     // 64 KB total (swizzled chunks)
    __shared__ ushort_t Vs[2][512][KVB];     // 64 KB total (linear)
    __shared__ ushort_t Ps[4 * 16 * PPAD];   // 5 KB
    __shared__ float alphaS[64];

    const int gid = blockIdx.x;
    const int b = gid & 3;
    const int h = (gid >> 2) & 1;
    const int p = gid >> 3;            // 0..31
    const int tid = threadIdx.x;
    const int w = tid >> 6, lane = tid & 63, c = lane & 15, g = lane >> 4;
    const int r = w & 3, d = w >> 2;   // row-group, role/D-half

    const int sbase = b * S_LEN;
    ushort_t* pw = Ps + r * 16 * PPAD;
    float* po = h ? out1 : out0;

    for (int phase = 0; phase < 2; ++phase) {
        const int jblk = phase ? (63 - p) : p;
        const int qbase = jblk * 64;
        const int tlast = 2 * jblk + 1;

        // Q fragments (1/sqrt(512) folded into W_q), QK waves only
        bf16x8 qf[16];
        if (d == 0) {
            const ushort_t* qrow = Q + (size_t)(sbase + qbase + r * 16 + c) * D_DIM;
#pragma unroll
            for (int kk = 0; kk < 16; kk++)
                qf[kk] = *(const bf16x8*)(qrow + kk * 32 + g * 8);
        }

        f32x4 o[16];
#pragma unroll
        for (int t = 0; t < 16; t++) o[t] = (f32x4){0.f, 0.f, 0.f, 0.f};
        float m_r[4], l_r[4];
#pragma unroll
        for (int jj = 0; jj < 4; jj++) { m_r[jj] = -1e30f; l_r[jj] = 0.f; }

        // ---- prologue: stage first tile into buf 0 ----
        {
            const int kv0 = h * KVB;
            const ushort_t* kg = K + (size_t)(sbase + kv0) * D_DIM;
#pragma unroll
            for (int ii = 0; ii < 4; ii++) {
                int row = w * 4 + ii;
                gll16(kg + (size_t)row * D_DIM + ((lane ^ (row & 7)) * 8), &Ks[0][row][0]);
            }
#pragma unroll
            for (int ii = 0; ii < 4; ii++) {
                int ch = w * 4 + ii;
                gll16(Vt + (size_t)(ch * 16 + (lane >> 2)) * NROW + sbase + kv0 + (lane & 3) * 8,
                      &Vs[0][ch * 16][0]);
            }
        }
        __syncthreads();   // buf0 staged (barrier drains vmcnt)

        int it = 0;
        for (int t = h; t <= tlast; t += 2, ++it) {
            const int cur = it & 1;

            // ---- issue async stage of tile t+2 into the other buffer ----
            if (t + 2 <= tlast) {
                const int kv0n = (t + 2) * KVB;
                const ushort_t* kg = K + (size_t)(sbase + kv0n) * D_DIM;
#pragma unroll
                for (int ii = 0; ii < 4; ii++) {
                    int row = w * 4 + ii;
                    gll16(kg + (size_t)row * D_DIM + ((lane ^ (row & 7)) * 8),
                          &Ks[cur ^ 1][row][0]);
                }
#pragma unroll
                for (int ii = 0; ii < 4; ii++) {
                    int ch = w * 4 + ii;
                    gll16(Vt + (size_t)(ch * 16 + (lane >> 2)) * NROW + sbase + kv0n + (lane & 3) * 8,
                          &Vs[cur ^ 1][ch * 16][0]);
                }
            }

            const int kv0 = t * KVB;
            float alpha[4];
            if (d == 0) {
                // ---- QK^T : S[16 q][32 kv] on swizzled K ----
                f32x4 s4[2];
#pragma unroll
                for (int nt = 0; nt < 2; nt++) {
                    f32x4 acc = (f32x4){0.f, 0.f, 0.f, 0.f};
#pragma unroll
                    for (int kk = 0; kk < 16; kk++) {
                        bf16x8 kf = *(const bf16x8*)(
                            &Ks[cur][nt * 16 + c][((4 * kk + g) ^ (c & 7)) * 8]);
                        acc = __builtin_amdgcn_mfma_f32_16x16x32_bf16(qf[kk], kf, acc, 0, 0, 0);
                    }
                    s4[nt] = acc;
                }

                // ---- causal mask (last tile of this parity) ----
                if (t >= 2 * jblk) {
#pragma unroll
                    for (int nt = 0; nt < 2; nt++)
#pragma unroll
                        for (int jj = 0; jj < 4; jj++) {
                            int qrow = qbase + r * 16 + g * 4 + jj;
                            int kvcol = kv0 + nt * 16 + c;
                            if (kvcol > qrow) s4[nt][jj] = -1e38f;
                        }
                }

                // ---- online softmax (full row in-wave; m floored at -1e30) ----
                float mx[4];
#pragma unroll
                for (int jj = 0; jj < 4; jj++) {
                    float v = fmaxf(s4[0][jj], s4[1][jj]);
#pragma unroll
                    for (int off = 1; off < 16; off <<= 1) v = fmaxf(v, __shfl_xor(v, off, 64));
                    mx[jj] = v;
                }
                float rs[4];
#pragma unroll
                for (int jj = 0; jj < 4; jj++) {
                    float mn = fmaxf(m_r[jj], mx[jj]);
                    alpha[jj] = __expf(m_r[jj] - mn);   // == 1.0f exactly when max unchanged
                    m_r[jj] = mn;
                    rs[jj] = 0.f;
                }
#pragma unroll
                for (int nt = 0; nt < 2; nt++)
#pragma unroll
                    for (int jj = 0; jj < 4; jj++) {
                        float pv = __expf(s4[nt][jj] - m_r[jj]);
                        rs[jj] += pv;
                        pw[(g * 4 + jj) * PPAD + nt * 16 + c] = f2bf(pv);
                    }
#pragma unroll
                for (int jj = 0; jj < 4; jj++) {
                    float v = rs[jj];
#pragma unroll
                    for (int off = 1; off < 16; off <<= 1) v += __shfl_xor(v, off, 64);
                    l_r[jj] = l_r[jj] * alpha[jj] + v;
                }
                if (c == 0) {
#pragma unroll
                    for (int jj = 0; jj < 4; jj++) alphaS[r * 16 + g * 4 + jj] = alpha[jj];
                }
            }
            __syncthreads();   // P + alphaS ready

            if (d == 1) {
#pragma unroll
                for (int jj = 0; jj < 4; jj++) alpha[jj] = alphaS[r * 16 + g * 4 + jj];
            }

            // ---- rescale O (wave-uniform skip when all alphas == 1) ----
            bool need = !(alpha[0] == 1.f && alpha[1] == 1.f && alpha[2] == 1.f && alpha[3] == 1.f);
            if (__any((int)need)) {
#pragma unroll
                for (int dt = 0; dt < 16; dt++)
#pragma unroll
                    for (int jj = 0; jj < 4; jj++) o[dt][jj] *= alpha[jj];
            }

            // ---- PV : O[16 rows][256 cols (d-half)] += P[16x32] * V[32x256] ----
            bf16x8 pf = *(const bf16x8*)(&pw[c * PPAD + g * 8]);
#pragma unroll
            for (int dt = 0; dt < 16; dt++) {
                bf16x8 vf = *(const bf16x8*)(&Vs[cur][d * 256 + dt * 16 + c][g * 8]);
                o[dt] = __builtin_amdgcn_mfma_f32_16x16x32_bf16(pf, vf, o[dt], 0, 0, 0);
            }

            __syncthreads();   // end of tile: stage(t+2) landed; all reads of buf[cur] done
        }

        // ---- write raw partial + (m,l) for this q-block ----
#pragma unroll
        for (int dt = 0; dt < 16; dt++)
#pragma unroll
            for (int jj = 0; jj < 4; jj++)
                po[(size_t)(sbase + qbase + r * 16 + g * 4 + jj) * D_DIM +
                   d * 256 + dt * 16 + c] = o[dt][jj];
        if (d == 0 && c == 0) {
#pragma unroll
            for (int jj = 0; jj < 4; jj++) {
                int row = sbase + qbase + r * 16 + g * 4 + jj;
                ml[((size_t)h * NROW + row) * 2 + 0] = m_r[jj];
                ml[((size_t)h * NROW + row) * 2 + 1] = l_r[jj];
            }
        }
        __syncthreads();   // Ps/alphaS safe to reuse next phase
    }
}

// ---------------- merge the two h-split partials ----------------
__global__ __launch_bounds__(256) void attn_merge_kernel(float* __restrict__ out,
                                                         const float* __restrict__ part1,
                                                         const float* __restrict__ ml) {
    int i = blockIdx.x * blockDim.x + threadIdx.x;   // float4 index
    int row = i >> 7;                                 // 128 float4 per row
    float m0 = ml[(size_t)row * 2 + 0], l0 = ml[(size_t)row * 2 + 1];
    float m1 = ml[((size_t)NROW + row) * 2 + 0], l1 = ml[((size_t)NROW + row) * 2 + 1];
    float mm = fmaxf(m0, m1);
    float a0 = __expf(m0 - mm), a1 = __expf(m1 - mm);
    float inv = 1.f / (l0 * a0 + l1 * a1);
    float4 x0 = reinterpret_cast<float4*>(out)[i];
    float4 x1 = reinterpret_cast<const float4*>(part1)[i];
    float4 r;
    r.x = (x0.x * a0 + x1.x * a1) * inv;
    r.y = (x0.y * a0 + x1.y * a1) * inv;
    r.z = (x0.z * a0 + x1.z * a1) * inv;
    r.w = (x0.w * a0 + x1.w * a1) * inv;
    reinterpret_cast<float4*>(out)[i] = r;
}

// ---------------- host launch ----------------
extern "C" void kernel_launch(void* const* d_in, const int* in_sizes, int n_in,
                              void* d_out, int out_size, void* d_ws, size_t ws_size,
                              hipStream_t stream) {
    const float* X  = (const float*)d_in[0];
    const float* Wq = (const float*)d_in[1];
    const float* Wk = (const float*)d_in[2];
    const float* Wv = (const float*)d_in[3];
    float* out = (float*)d_out;

    const int M = NROW;             // 16384
    const int Kd = D_DIM;           // 512
    const size_t XBF_BYTES = (size_t)M * Kd * 2;
    const size_t W_BYTES   = (size_t)Kd * Kd * 2;

    char* p = (char*)d_ws;
    ushort_t* Xbf = (ushort_t*)p;              p += XBF_BYTES;
    ushort_t* Wqb = (ushort_t*)p;              p += W_BYTES;
    ushort_t* Wkb = (ushort_t*)p;              p += W_BYTES;
    ushort_t* Wvb = (ushort_t*)p;              p += W_BYTES;
    ushort_t* Qb  = (ushort_t*)p;              p += XBF_BYTES;
    ushort_t* Kb  = (ushort_t*)p;              p += XBF_BYTES;
    ushort_t* Vtb = (ushort_t*)p;              p += XBF_BYTES;
    float*    part1 = (float*)p;               p += (size_t)M * Kd * 4;  // 32 MB
    float*    ml    = (float*)p;               p += (size_t)2 * M * 2 * 4;

    const float qscale = 0.044194173824159216f;  // 1/sqrt(512)

    {
        int n4 = (M * Kd) / 4;
        cvt_bf16_kernel<<<(n4 + 255) / 256, 256, 0, stream>>>(X, Xbf, n4, 1.0f);
        int w4 = (Kd * Kd) / 4;
        cvt_bf16_kernel<<<(w4 + 255) / 256, 256, 0, stream>>>(Wq, Wqb, w4, qscale);
        cvt_bf16_kernel<<<(w4 + 255) / 256, 256, 0, stream>>>(Wk, Wkb, w4, 1.0f);
        cvt_bf16_kernel<<<(w4 + 255) / 256, 256, 0, stream>>>(Wv, Wvb, w4, 1.0f);
    }
    gemm_bt<<<dim3(M / 128, Kd / 128), 256, 0, stream>>>(Xbf, Wqb, Qb, M, Kd, Kd);
    gemm_bt<<<dim3(M / 128, Kd / 128), 256, 0, stream>>>(Xbf, Wkb, Kb, M, Kd, Kd);
    gemm_bt<<<dim3(Kd / 128, M / 128), 256, 0, stream>>>(Wvb, Xbf, Vtb, Kd, M, Kd);

    attn_part_kernel<<<256, 512, 0, stream>>>(Qb, Kb, Vtb, out, part1, ml);
    attn_merge_kernel<<<(M * Kd / 4) / 256, 256, 0, stream>>>(out, part1, ml);
}

// Round 8
// 277.438 us; speedup vs baseline: 1.2315x; 1.0585x over previous
//
#include <hip/hip_runtime.h>
#include <hip/hip_bf16.h>

typedef __bf16 bf16x8 __attribute__((ext_vector_type(8)));
typedef float f32x4 __attribute__((ext_vector_type(4)));
typedef unsigned short ushort_t;

#define S_LEN 4096
#define D_DIM 512
#define NBATCH 4
#define NROW (NBATCH * S_LEN)

static __device__ __forceinline__ ushort_t f2bf(float f) {
    __hip_bfloat16 h = __float2bfloat16(f);
    return __builtin_bit_cast(ushort_t, h);
}

typedef unsigned int __attribute__((address_space(1))) as1_uint;
typedef unsigned int __attribute__((address_space(3))) as3_uint;

// async 16B/lane global->LDS (wave-uniform LDS base + lane*16; global src per-lane)
static __device__ __forceinline__ void gll16(const ushort_t* src, ushort_t* dst) {
    __builtin_amdgcn_global_load_lds((const as1_uint*)(const void*)src,
                                     (as3_uint*)(void*)dst, 16, 0, 0);
}

// ---------------- fp32 -> bf16 convert (with optional scale) ----------------
__global__ void cvt_bf16_kernel(const float* __restrict__ src, ushort_t* __restrict__ dst,
                                int n4, float scale) {
    int i = blockIdx.x * blockDim.x + threadIdx.x;
    if (i >= n4) return;
    float4 v = reinterpret_cast<const float4*>(src)[i];
    ushort4 o;
    o.x = f2bf(v.x * scale);
    o.y = f2bf(v.y * scale);
    o.z = f2bf(v.z * scale);
    o.w = f2bf(v.w * scale);
    reinterpret_cast<ushort4*>(dst)[i] = o;
}

// ---------------- generic bf16 GEMM: C[M][N] = A[M][K] * Bt[N][K]^T ----------------
__global__ __launch_bounds__(256) void gemm_bt(const ushort_t* __restrict__ A,
                                               const ushort_t* __restrict__ Bt,
                                               ushort_t* __restrict__ C,
                                               int M, int N, int K) {
    __shared__ ushort_t As[128 * 40];
    __shared__ ushort_t Bs[128 * 40];
    int tid = threadIdx.x;
    int w = tid >> 6, lane = tid & 63, c = lane & 15, g = lane >> 4;
    int m0 = blockIdx.x * 128, n0 = blockIdx.y * 128;
    int wm = (w >> 1) * 64, wn = (w & 1) * 64;

    f32x4 acc[4][4];
#pragma unroll
    for (int mi = 0; mi < 4; mi++)
#pragma unroll
        for (int ni = 0; ni < 4; ni++) acc[mi][ni] = (f32x4){0.f, 0.f, 0.f, 0.f};

    for (int k0 = 0; k0 < K; k0 += 32) {
        __syncthreads();
#pragma unroll
        for (int r = 0; r < 2; r++) {
            int cl = r * 256 + tid;
            int row = cl >> 2, cin = cl & 3;
            *(bf16x8*)(&As[row * 40 + cin * 8]) =
                *(const bf16x8*)(A + (size_t)(m0 + row) * K + k0 + cin * 8);
            *(bf16x8*)(&Bs[row * 40 + cin * 8]) =
                *(const bf16x8*)(Bt + (size_t)(n0 + row) * K + k0 + cin * 8);
        }
        __syncthreads();

        bf16x8 af[4], bfr[4];
#pragma unroll
        for (int i2 = 0; i2 < 4; i2++)
            af[i2] = *(const bf16x8*)(&As[(wm + i2 * 16 + c) * 40 + g * 8]);
#pragma unroll
        for (int i2 = 0; i2 < 4; i2++)
            bfr[i2] = *(const bf16x8*)(&Bs[(wn + i2 * 16 + c) * 40 + g * 8]);
#pragma unroll
        for (int mi = 0; mi < 4; mi++)
#pragma unroll
            for (int ni = 0; ni < 4; ni++)
                acc[mi][ni] = __builtin_amdgcn_mfma_f32_16x16x32_bf16(af[mi], bfr[ni],
                                                                      acc[mi][ni], 0, 0, 0);
    }

#pragma unroll
    for (int mi = 0; mi < 4; mi++)
#pragma unroll
        for (int ni = 0; ni < 4; ni++)
#pragma unroll
            for (int j = 0; j < 4; j++)
                C[(size_t)(m0 + wm + mi * 16 + g * 4 + j) * N + n0 + wn + ni * 16 + c] =
                    f2bf(acc[mi][ni][j]);
}

// ------------- flash attention partials: swapped-QK, independent waves, 1 barrier/tile -------------
// 256 WGs of 512 threads. WG (b, p, h): q-blocks j=p then 63-p; kv tiles t%2==h (KVB=32, dbuf).
// Waves (r 0..3, d 0..1): BOTH d compute swapped QK^T (S^T: q=lane&15) for rows r*16+..;
// per-lane scalar softmax (2 shfl_xor); P packed to wave-PRIVATE LDS (no barrier);
// PV on D-half d. K and V LDS XOR-swizzled via pre-swizzled gll16 sources.
#define KVB 32
#define PPAD 40

__global__ __launch_bounds__(512, 2) void attn_part_kernel(const ushort_t* __restrict__ Q,
                                                           const ushort_t* __restrict__ K,
                                                           const ushort_t* __restrict__ Vt,
                                                           float* __restrict__ out0,
                                                           float* __restrict__ out1,
                                                           float* __restrict__ ml) {
    __shared__ ushort_t Ks[2][KVB][512];      // 64 KB (chunk-swizzled: pos = ch ^ (row&7))
    __shared__ ushort_t Vs[2][512][KVB];      // 64 KB (chunk-swizzled: pos = ch ^ ((rr^(rr>>2))&3))
    __shared__ ushort_t Ps[8 * 16 * PPAD];    // 10 KB, per-wave private

    const int gid = blockIdx.x;
    const int b = gid & 3;
    const int h = (gid >> 2) & 1;
    const int p = gid >> 3;            // 0..31
    const int tid = threadIdx.x;
    const int w = tid >> 6, lane = tid & 63, c = lane & 15, g = lane >> 4;
    const int r = w & 3, d = w >> 2;   // row-group, D-half

    const int sbase = b * S_LEN;
    ushort_t* pw = Ps + w * 16 * PPAD;
    float* po = h ? out1 : out0;
    const int hc = (c ^ (c >> 2)) & 3;            // V-read swizzle hash
    const int vrr = lane >> 2, vpc = lane & 3;    // V-stage row/chunk within 16-row group
    const int vhh = (vrr ^ (vrr >> 2)) & 3;       // V-stage swizzle hash

    for (int phase = 0; phase < 2; ++phase) {
        const int jblk = phase ? (63 - p) : p;
        const int qbase = jblk * 64;
        const int tlast = 2 * jblk + 1;

        // Q fragments (1/sqrt(512) folded into W_q); d-pair waves load the same 16 rows.
        bf16x8 qf[16];
        {
            const ushort_t* qrow = Q + (size_t)(sbase + qbase + r * 16 + c) * D_DIM;
#pragma unroll
            for (int kk = 0; kk < 16; kk++)
                qf[kk] = *(const bf16x8*)(qrow + kk * 32 + g * 8);
        }

        f32x4 o[16];
#pragma unroll
        for (int t = 0; t < 16; t++) o[t] = (f32x4){0.f, 0.f, 0.f, 0.f};
        float m_r = -1e30f, l_r = 0.f;   // per-lane: q-row = r*16 + c

        // ---- prologue: stage first tile into buf 0 ----
        {
            const int kv0 = h * KVB;
            const ushort_t* kg = K + (size_t)(sbase + kv0) * D_DIM;
#pragma unroll
            for (int ii = 0; ii < 4; ii++) {
                int row = w * 4 + ii;
                gll16(kg + (size_t)row * D_DIM + ((lane ^ (row & 7)) * 8), &Ks[0][row][0]);
            }
#pragma unroll
            for (int ii = 0; ii < 4; ii++) {
                int ch = w * 4 + ii;
                gll16(Vt + (size_t)(ch * 16 + vrr) * NROW + sbase + kv0 + ((vpc ^ vhh) * 8),
                      &Vs[0][ch * 16][0]);
            }
        }
        __syncthreads();   // buf0 staged (barrier drains vmcnt)

        int it = 0;
        for (int t = h; t <= tlast; t += 2, ++it) {
            const int cur = it & 1;

            // ---- issue async stage of tile t+2 into the other buffer ----
            if (t + 2 <= tlast) {
                const int kv0n = (t + 2) * KVB;
                const ushort_t* kg = K + (size_t)(sbase + kv0n) * D_DIM;
#pragma unroll
                for (int ii = 0; ii < 4; ii++) {
                    int row = w * 4 + ii;
                    gll16(kg + (size_t)row * D_DIM + ((lane ^ (row & 7)) * 8),
                          &Ks[cur ^ 1][row][0]);
                }
#pragma unroll
                for (int ii = 0; ii < 4; ii++) {
                    int ch = w * 4 + ii;
                    gll16(Vt + (size_t)(ch * 16 + vrr) * NROW + sbase + kv0n + ((vpc ^ vhh) * 8),
                          &Vs[cur ^ 1][ch * 16][0]);
                }
            }

            const int kv0 = t * KVB;

            // ---- swapped QK^T : S^T[kv][q], every wave, own 16 rows ----
            f32x4 s4[2];
#pragma unroll
            for (int nt = 0; nt < 2; nt++) {
                f32x4 acc = (f32x4){0.f, 0.f, 0.f, 0.f};
#pragma unroll
                for (int kk = 0; kk < 16; kk++) {
                    bf16x8 kf = *(const bf16x8*)(
                        &Ks[cur][nt * 16 + c][((4 * kk + g) ^ (c & 7)) * 8]);
                    acc = __builtin_amdgcn_mfma_f32_16x16x32_bf16(kf, qf[kk], acc, 0, 0, 0);
                }
                s4[nt] = acc;   // s4[nt][jj] = S[kv = kv0 + nt*16 + g*4 + jj][q = r*16 + c]
            }

            // ---- causal mask (diagonal 64-block tiles) ----
            if (t >= 2 * jblk) {
                int qrow = qbase + r * 16 + c;
#pragma unroll
                for (int nt = 0; nt < 2; nt++)
#pragma unroll
                    for (int jj = 0; jj < 4; jj++) {
                        int kvcol = kv0 + nt * 16 + g * 4 + jj;
                        if (kvcol > qrow) s4[nt][jj] = -1e38f;
                    }
            }

            // ---- per-lane online softmax (row q = r*16+c spread over 4 g-groups) ----
            float pm = s4[0][0];
#pragma unroll
            for (int jj = 1; jj < 4; jj++) pm = fmaxf(pm, s4[0][jj]);
#pragma unroll
            for (int jj = 0; jj < 4; jj++) pm = fmaxf(pm, s4[1][jj]);
            pm = fmaxf(pm, __shfl_xor(pm, 16, 64));
            pm = fmaxf(pm, __shfl_xor(pm, 32, 64));
            float mn = fmaxf(m_r, pm);
            float alpha = __expf(m_r - mn);   // == 1.0f exactly when max unchanged
            m_r = mn;

            float pv[2][4], rs = 0.f;
#pragma unroll
            for (int nt = 0; nt < 2; nt++)
#pragma unroll
                for (int jj = 0; jj < 4; jj++) {
                    pv[nt][jj] = __expf(s4[nt][jj] - mn);
                    rs += pv[nt][jj];
                }
            rs += __shfl_xor(rs, 16, 64);
            rs += __shfl_xor(rs, 32, 64);
            l_r = l_r * alpha + rs;

            // ---- pack P to wave-private LDS (no barrier: same-wave write->read) ----
#pragma unroll
            for (int nt = 0; nt < 2; nt++) {
                ushort4 u;
                u.x = f2bf(pv[nt][0]);
                u.y = f2bf(pv[nt][1]);
                u.z = f2bf(pv[nt][2]);
                u.w = f2bf(pv[nt][3]);
                *(ushort4*)(&pw[c * PPAD + nt * 16 + g * 4]) = u;
            }
            bf16x8 pa = *(const bf16x8*)(&pw[c * PPAD + g * 8]);

            // ---- rescale O (wave-uniform skip when all alphas == 1) ----
            if (__any((int)(alpha != 1.f))) {
                float aq[4];
#pragma unroll
                for (int jj = 0; jj < 4; jj++)
                    aq[jj] = __shfl(alpha, (lane & 48) | (g * 4 + jj), 64);
#pragma unroll
                for (int dt = 0; dt < 16; dt++)
#pragma unroll
                    for (int jj = 0; jj < 4; jj++) o[dt][jj] *= aq[jj];
            }

            // ---- PV : O[16 rows][256 cols (d-half)] += P[16x32] * V[32x256] ----
#pragma unroll
            for (int dt = 0; dt < 16; dt++) {
                bf16x8 vf = *(const bf16x8*)(&Vs[cur][d * 256 + dt * 16 + c][(g ^ hc) * 8]);
                o[dt] = __builtin_amdgcn_mfma_f32_16x16x32_bf16(pa, vf, o[dt], 0, 0, 0);
            }

            __syncthreads();   // end of tile: stage(t+2) landed; all reads of buf[cur] done
        }

        // ---- write raw partial + (m,l) for this q-block ----
#pragma unroll
        for (int dt = 0; dt < 16; dt++)
#pragma unroll
            for (int jj = 0; jj < 4; jj++)
                po[(size_t)(sbase + qbase + r * 16 + g * 4 + jj) * D_DIM +
                   d * 256 + dt * 16 + c] = o[dt][jj];
        if (d == 0 && g == 0) {
            int row = sbase + qbase + r * 16 + c;
            ml[((size_t)h * NROW + row) * 2 + 0] = m_r;
            ml[((size_t)h * NROW + row) * 2 + 1] = l_r;
        }
    }
}

// ---------------- merge the two h-split partials ----------------
__global__ __launch_bounds__(256) void attn_merge_kernel(float* __restrict__ out,
                                                         const float* __restrict__ part1,
                                                         const float* __restrict__ ml) {
    int i = blockIdx.x * blockDim.x + threadIdx.x;   // float4 index
    int row = i >> 7;                                 // 128 float4 per row
    float m0 = ml[(size_t)row * 2 + 0], l0 = ml[(size_t)row * 2 + 1];
    float m1 = ml[((size_t)NROW + row) * 2 + 0], l1 = ml[((size_t)NROW + row) * 2 + 1];
    float mm = fmaxf(m0, m1);
    float a0 = __expf(m0 - mm), a1 = __expf(m1 - mm);
    float inv = 1.f / (l0 * a0 + l1 * a1);
    float4 x0 = reinterpret_cast<float4*>(out)[i];
    float4 x1 = reinterpret_cast<const float4*>(part1)[i];
    float4 r;
    r.x = (x0.x * a0 + x1.x * a1) * inv;
    r.y = (x0.y * a0 + x1.y * a1) * inv;
    r.z = (x0.z * a0 + x1.z * a1) * inv;
    r.w = (x0.w * a0 + x1.w * a1) * inv;
    reinterpret_cast<float4*>(out)[i] = r;
}

// ---------------- host launch ----------------
extern "C" void kernel_launch(void* const* d_in, const int* in_sizes, int n_in,
                              void* d_out, int out_size, void* d_ws, size_t ws_size,
                              hipStream_t stream) {
    const float* X  = (const float*)d_in[0];
    const float* Wq = (const float*)d_in[1];
    const float* Wk = (const float*)d_in[2];
    const float* Wv = (const float*)d_in[3];
    float* out = (float*)d_out;

    const int M = NROW;             // 16384
    const int Kd = D_DIM;           // 512
    const size_t XBF_BYTES = (size_t)M * Kd * 2;
    const size_t W_BYTES   = (size_t)Kd * Kd * 2;

    char* p = (char*)d_ws;
    ushort_t* Xbf = (ushort_t*)p;              p += XBF_BYTES;
    ushort_t* Wqb = (ushort_t*)p;              p += W_BYTES;
    ushort_t* Wkb = (ushort_t*)p;              p += W_BYTES;
    ushort_t* Wvb = (ushort_t*)p;              p += W_BYTES;
    ushort_t* Qb  = (ushort_t*)p;              p += XBF_BYTES;
    ushort_t* Kb  = (ushort_t*)p;              p += XBF_BYTES;
    ushort_t* Vtb = (ushort_t*)p;              p += XBF_BYTES;
    float*    part1 = (float*)p;               p += (size_t)M * Kd * 4;  // 32 MB
    float*    ml    = (float*)p;               p += (size_t)2 * M * 2 * 4;

    const float qscale = 0.044194173824159216f;  // 1/sqrt(512)

    {
        int n4 = (M * Kd) / 4;
        cvt_bf16_kernel<<<(n4 + 255) / 256, 256, 0, stream>>>(X, Xbf, n4, 1.0f);
        int w4 = (Kd * Kd) / 4;
        cvt_bf16_kernel<<<(w4 + 255) / 256, 256, 0, stream>>>(Wq, Wqb, w4, qscale);
        cvt_bf16_kernel<<<(w4 + 255) / 256, 256, 0, stream>>>(Wk, Wkb, w4, 1.0f);
        cvt_bf16_kernel<<<(w4 + 255) / 256, 256, 0, stream>>>(Wv, Wvb, w4, 1.0f);
    }
    gemm_bt<<<dim3(M / 128, Kd / 128), 256, 0, stream>>>(Xbf, Wqb, Qb, M, Kd, Kd);
    gemm_bt<<<dim3(M / 128, Kd / 128), 256, 0, stream>>>(Xbf, Wkb, Kb, M, Kd, Kd);
    gemm_bt<<<dim3(Kd / 128, M / 128), 256, 0, stream>>>(Wvb, Xbf, Vtb, Kd, M, Kd);

    attn_part_kernel<<<256, 512, 0, stream>>>(Qb, Kb, Vtb, out, part1, ml);
    attn_merge_kernel<<<(M * Kd / 4) / 256, 256, 0, stream>>>(out, part1, ml);
}